// Round 5
// baseline (197.375 us; speedup 1.0000x reference)
//
#include <hip/hip_runtime.h>

#define NS 10000
#define DD 64
#define HH 128
#define EE 50000
#define SLOPE 0.01f

typedef __attribute__((ext_vector_type(8))) short short8;
typedef __attribute__((ext_vector_type(4))) float f32x4;

static __device__ __forceinline__ unsigned short f2bf(float f) {
  unsigned int u = __float_as_uint(f);
  u += 0x7fff + ((u >> 16) & 1);   // round-to-nearest-even
  return (unsigned short)(u >> 16);
}

__device__ __forceinline__ float wave_sum64(float v) {
  #pragma unroll
  for (int m = 32; m >= 1; m >>= 1) v += __shfl_xor(v, m, 64);
  return v;
}

// h = leaky_relu(layer_norm(x)) (+bf16 copy). Also folds degree counting
// (grid 2500x256 = 640k threads covers E=50k).
__global__ __launch_bounds__(256) void k_ln(const float* __restrict__ x,
    const float* __restrict__ gamma, const float* __restrict__ beta,
    float* __restrict__ h, unsigned short* __restrict__ hbf,
    const int* __restrict__ ei, int* __restrict__ cntsrc,
    int* __restrict__ cntdst) {
  int gid = blockIdx.x * 256 + threadIdx.x;
  if (gid < EE) {
    atomicAdd(&cntsrc[ei[gid]], 1);
    atomicAdd(&cntdst[ei[EE + gid]], 1);
  }
  int wid = threadIdx.x >> 6;
  int lane = threadIdx.x & 63;
  int row = blockIdx.x * 4 + wid;
  if (row >= NS) return;
  float v = x[row * DD + lane];
  float s = wave_sum64(v);
  float s2 = wave_sum64(v * v);
  float mu = s * (1.0f / 64.0f);
  float var = s2 * (1.0f / 64.0f) - mu * mu;
  float r = rsqrtf(var + 1e-5f);
  float hn = (v - mu) * r * gamma[lane] + beta[lane];
  float hv = hn >= 0.f ? hn : SLOPE * hn;
  h[row * DD + lane] = hv;
  hbf[row * DD + lane] = f2bf(hv);
}

// w2t2[(f*128+k)*64 + d] = bf16(w2[k*4096 + d*64 + f])  (c2 = f*128+k order)
__global__ __launch_bounds__(256) void k_cast_w2t2(const float* __restrict__ w2,
    unsigned short* __restrict__ w2t2) {
  int tid = blockIdx.x * 256 + threadIdx.x;   // 524288
  int d = tid & 63;
  int c2 = tid >> 6;
  int f = c2 >> 7, k = c2 & 127;
  w2t2[tid] = f2bf(w2[k * (DD * DD) + d * DD + f]);
}

// ubf = bf16(leaky_relu(ea @ w1 + b1))   [E,64]@[64,128]
__global__ __launch_bounds__(256) void k_u(const float* __restrict__ ea,
    const float* __restrict__ w1, const float* __restrict__ b1,
    unsigned short* __restrict__ ubf) {
  __shared__ float w1s[DD][HH];
  __shared__ float eas[32][DD];
  int t = threadIdx.x;
  #pragma unroll
  for (int i = 0; i < 32; ++i) {
    int idx = t + i * 256;
    w1s[idx >> 7][idx & 127] = w1[idx];
  }
  int row0 = blockIdx.x * 32;
  #pragma unroll
  for (int i = 0; i < 8; ++i) {
    int idx = t + i * 256;
    int r = idx >> 6, d = idx & 63;
    int gr = row0 + r;
    eas[r][d] = (gr < EE) ? ea[gr * DD + d] : 0.f;
  }
  __syncthreads();
  int r = t >> 3;
  int c0 = (t & 7) * 16;
  int gr = row0 + r;
  if (gr >= EE) return;
  float acc[16];
  #pragma unroll
  for (int j = 0; j < 16; ++j) acc[j] = b1[c0 + j];
  for (int d = 0; d < DD; ++d) {
    float a = eas[r][d];
    #pragma unroll
    for (int j = 0; j < 16; ++j) acc[j] += a * w1s[d][c0 + j];
  }
  #pragma unroll
  for (int j = 0; j < 16; ++j) {
    float vv = acc[j];
    ubf[(size_t)gr * HH + c0 + j] = f2bf(vv >= 0.f ? vv : SLOPE * vv);
  }
}

// C[n,64] = A[n,64] @ B[64,64]
__global__ __launch_bounds__(256) void k_gemm64(const float* __restrict__ A,
    const float* __restrict__ B, float* __restrict__ C, int n) {
  __shared__ float Bs[DD][DD + 1];
  __shared__ float As[32][DD];
  int t = threadIdx.x;
  #pragma unroll
  for (int i = 0; i < 16; ++i) {
    int idx = t + i * 256;
    Bs[idx >> 6][idx & 63] = B[idx];
  }
  int row0 = blockIdx.x * 32;
  #pragma unroll
  for (int i = 0; i < 8; ++i) {
    int idx = t + i * 256;
    int r = idx >> 6, d = idx & 63;
    int gr = row0 + r;
    As[r][d] = (gr < n) ? A[gr * DD + d] : 0.f;
  }
  __syncthreads();
  int r = t >> 3;
  int c0 = (t & 7) * 8;
  int gr = row0 + r;
  if (gr >= n) return;
  float acc[8] = {};
  for (int d = 0; d < DD; ++d) {
    float a = As[r][d];
    #pragma unroll
    for (int j = 0; j < 8; ++j) acc[j] += a * Bs[d][c0 + j];
  }
  #pragma unroll
  for (int j = 0; j < 8; ++j) C[(size_t)gr * DD + c0 + j] = acc[j];
}

// single-block exclusive scan of cntsrc -> rowptr[N+1], also init cursor.
__global__ __launch_bounds__(1024) void k_scan(const int* __restrict__ cntsrc,
    int* __restrict__ rowptr, int* __restrict__ cursor) {
  __shared__ int ps[1024];
  int t = threadIdx.x;
  const int CH = (NS + 1023) / 1024;
  int base = t * CH;
  int sum = 0;
  for (int i = 0; i < CH; ++i) {
    int idx = base + i;
    if (idx < NS) sum += cntsrc[idx];
  }
  ps[t] = sum;
  __syncthreads();
  for (int off = 1; off < 1024; off <<= 1) {
    int v = (t >= off) ? ps[t - off] : 0;
    __syncthreads();
    ps[t] += v;
    __syncthreads();
  }
  int run = ps[t] - sum;
  for (int i = 0; i < CH; ++i) {
    int idx = base + i;
    if (idx < NS) {
      rowptr[idx] = run;
      cursor[idx] = run;
      run += cntsrc[idx];
    }
  }
  if (t == 1023) rowptr[NS] = run;
}

__global__ __launch_bounds__(256) void k_scatter(const int* __restrict__ ei,
    int* __restrict__ cursor, int* __restrict__ eord) {
  int e = blockIdx.x * 256 + threadIdx.x;
  if (e < EE) {
    int s = ei[e];
    int pos = atomicAdd(&cursor[s], 1);
    eord[pos] = e;
  }
}

// Tt[(n-n0)*8192 + c2] (bf16) = sum_d hbf[n,d] * w2t2[c2,d], c2 = f*128+k.
// Tile 64 rows x 256 cols, 4 waves.
__global__ __launch_bounds__(256) void k_T_mfma(
    const unsigned short* __restrict__ hbf, const unsigned short* __restrict__ w2t2,
    unsigned short* __restrict__ T, int n0, int n1) {
  __shared__ unsigned short As[64][72];
  __shared__ unsigned short Bs[256][72];
  int t = threadIdx.x;
  int row0 = n0 + blockIdx.x * 64;
  int col0 = blockIdx.y * 256;
  #pragma unroll
  for (int i = 0; i < 2; ++i) {
    int idx = t + i * 256;
    int r = idx >> 3, cc = (idx & 7) * 8;
    int gr = row0 + r;
    short8 v = {};
    if (gr < n1) v = *(const short8*)(hbf + (size_t)gr * DD + cc);
    *(short8*)(&As[r][cc]) = v;
  }
  #pragma unroll
  for (int i = 0; i < 8; ++i) {
    int idx = t + i * 256;
    int cL = idx >> 3, rr = (idx & 7) * 8;
    int gc = col0 + cL;
    short8 v = *(const short8*)(w2t2 + (size_t)gc * DD + rr);
    *(short8*)(&Bs[cL][rr]) = v;
  }
  __syncthreads();
  int w = t >> 6, lane = t & 63;
  int lr = lane & 15, lg = lane >> 4;
  f32x4 acc[4][4] = {};
  #pragma unroll
  for (int kk = 0; kk < 64; kk += 32) {
    short8 a[4], b[4];
    #pragma unroll
    for (int mi = 0; mi < 4; ++mi)
      a[mi] = *(const short8*)(&As[mi * 16 + lr][kk + lg * 8]);
    #pragma unroll
    for (int ni = 0; ni < 4; ++ni)
      b[ni] = *(const short8*)(&Bs[w * 64 + ni * 16 + lr][kk + lg * 8]);
    #pragma unroll
    for (int mi = 0; mi < 4; ++mi)
      #pragma unroll
      for (int ni = 0; ni < 4; ++ni)
        acc[mi][ni] = __builtin_amdgcn_mfma_f32_16x16x32_bf16(
            a[mi], b[ni], acc[mi][ni], 0, 0, 0);
  }
  #pragma unroll
  for (int mi = 0; mi < 4; ++mi) {
    int gr0 = row0 + mi * 16 + lg * 4;
    #pragma unroll
    for (int ni = 0; ni < 4; ++ni) {
      int gc = col0 + w * 64 + ni * 16 + lr;
      #pragma unroll
      for (int reg = 0; reg < 4; ++reg) {
        int gr = gr0 + reg;
        if (gr < n1)
          T[(size_t)(gr - n0) * (HH * DD) + gc] = f2bf(acc[mi][ni][reg]);
      }
    }
  }
}

// Wave-per-node message pass: B-frags = Tt[s] (16KB, read once), A-frags =
// gathered bf16 u-rows of <=16 edges; 16 MFMA -> msg tile; +cc; atomic flush.
__global__ __launch_bounds__(256) void k_msg_wave(
    const unsigned short* __restrict__ ubf, const unsigned short* __restrict__ T,
    const float* __restrict__ cc, const int* __restrict__ ei,
    const int* __restrict__ rowptr, const int* __restrict__ eord,
    float* __restrict__ agg, int n0, int n1) {
  int wid = threadIdx.x >> 6;
  int lane = threadIdx.x & 63;
  int s = n0 + blockIdx.x * 4 + wid;
  if (s >= n1) return;
  int beg = rowptr[s];
  int deg = rowptr[s + 1] - beg;
  if (deg == 0) return;
  int lr = lane & 15, lg = lane >> 4;
  const unsigned short* tp = T + (size_t)(s - n0) * (HH * DD);
  short8 b[4][4];   // [ftile][kstep]
  #pragma unroll
  for (int ft = 0; ft < 4; ++ft)
    #pragma unroll
    for (int kk = 0; kk < 4; ++kk)
      b[ft][kk] =
          *(const short8*)(tp + (ft * 16 + lr) * HH + kk * 32 + lg * 8);
  float clv[4];
  #pragma unroll
  for (int ft = 0; ft < 4; ++ft) clv[ft] = cc[(size_t)s * DD + ft * 16 + lr];

  for (int p0 = 0; p0 < deg; p0 += 16) {
    int ev = 0, dv = 0;
    if (lane < 16 && p0 + lane < deg) {
      ev = eord[beg + p0 + lane];
      dv = ei[EE + ev];
    }
    int e_lr = __shfl(ev, (p0 + lr < deg) ? lr : 0);
    const unsigned short* up = ubf + (size_t)e_lr * HH;
    short8 a[4];
    #pragma unroll
    for (int kk = 0; kk < 4; ++kk)
      a[kk] = *(const short8*)(up + kk * 32 + lg * 8);
    f32x4 acc[4] = {};
    #pragma unroll
    for (int kk = 0; kk < 4; ++kk)
      #pragma unroll
      for (int ft = 0; ft < 4; ++ft)
        acc[ft] = __builtin_amdgcn_mfma_f32_16x16x32_bf16(a[kk], b[ft][kk],
                                                          acc[ft], 0, 0, 0);
    #pragma unroll
    for (int r = 0; r < 4; ++r) {
      int idx = p0 + lg * 4 + r;
      int dstn = __shfl(dv, lg * 4 + r);
      if (idx < deg) {
        #pragma unroll
        for (int ft = 0; ft < 4; ++ft)
          atomicAdd(&agg[(size_t)dstn * DD + ft * 16 + lr],
                    acc[ft][r] + clv[ft]);
      }
    }
  }
}

// out = x + agg/max(cnt,1) + h@root + bias
__global__ __launch_bounds__(256) void k_final(const float* __restrict__ x,
    const float* __restrict__ h, const float* __restrict__ root,
    const float* __restrict__ bias, const float* __restrict__ agg,
    const int* __restrict__ cnt, float* __restrict__ out) {
  __shared__ float Bs[DD][DD + 1];
  __shared__ float As[32][DD];
  int t = threadIdx.x;
  #pragma unroll
  for (int i = 0; i < 16; ++i) {
    int idx = t + i * 256;
    Bs[idx >> 6][idx & 63] = root[idx];
  }
  int row0 = blockIdx.x * 32;
  #pragma unroll
  for (int i = 0; i < 8; ++i) {
    int idx = t + i * 256;
    int r = idx >> 6, d = idx & 63;
    int gr = row0 + r;
    As[r][d] = (gr < NS) ? h[gr * DD + d] : 0.f;
  }
  __syncthreads();
  int r = t >> 3;
  int c0 = (t & 7) * 8;
  int gr = row0 + r;
  if (gr >= NS) return;
  float acc[8] = {};
  for (int d = 0; d < DD; ++d) {
    float a = As[r][d];
    #pragma unroll
    for (int j = 0; j < 8; ++j) acc[j] += a * Bs[d][c0 + j];
  }
  float inv = 1.0f / fmaxf((float)cnt[gr], 1.0f);
  #pragma unroll
  for (int j = 0; j < 8; ++j) {
    size_t gi = (size_t)gr * DD + c0 + j;
    out[gi] = x[gi] + agg[gi] * inv + acc[j] + bias[c0 + j];
  }
}

extern "C" void kernel_launch(void* const* d_in, const int* in_sizes, int n_in,
                              void* d_out, int out_size, void* d_ws, size_t ws_size,
                              hipStream_t stream) {
  const float* x     = (const float*)d_in[0];
  const float* ea    = (const float*)d_in[1];
  const float* gamma = (const float*)d_in[2];
  const float* beta  = (const float*)d_in[3];
  const float* w1    = (const float*)d_in[4];
  const float* b1    = (const float*)d_in[5];
  const float* w2    = (const float*)d_in[6];
  const float* b2    = (const float*)d_in[7];
  const float* root  = (const float*)d_in[8];
  const float* bias  = (const float*)d_in[9];
  const int*   ei    = (const int*)d_in[10];
  float* out = (float*)d_out;

  char* p = (char*)d_ws;
  auto carve = [&](size_t bytes) {
    char* q = p;
    p += (bytes + 255) & ~(size_t)255;
    return q;
  };
  float* h             = (float*)carve(sizeof(float) * NS * DD);
  unsigned short* hbf  = (unsigned short*)carve(sizeof(short) * NS * DD);
  float* cc            = (float*)carve(sizeof(float) * NS * DD);
  unsigned short* w2t2 = (unsigned short*)carve(sizeof(short) * HH * DD * DD);
  unsigned short* ubf  = (unsigned short*)carve(sizeof(short) * (size_t)EE * HH);
  int* rowptr          = (int*)carve(sizeof(int) * (NS + 1));
  int* cursor          = (int*)carve(sizeof(int) * NS);
  int* eord            = (int*)carve(sizeof(int) * EE);
  // contiguous zero-region: agg | cntdst | cntsrc (single memset)
  char* z0 = p;
  float* agg           = (float*)carve(sizeof(float) * NS * DD);
  int* cntdst          = (int*)carve(sizeof(int) * NS);
  int* cntsrc          = (int*)carve(sizeof(int) * NS);
  size_t zlen = (size_t)(p - z0);
  size_t fixed = (size_t)(p - (char*)d_ws);

  // LLC-resident T chunk: target 2560 nodes (42 MB), shrink if ws is tight.
  size_t freeb = (ws_size > fixed) ? (ws_size - fixed - 256) : 0;
  int rows = (int)(freeb / (sizeof(short) * HH * DD));
  if (rows > 2560) rows = 2560;
  rows &= ~63;
  if (rows < 64) rows = 64;
  unsigned short* Tt = (unsigned short*)carve(sizeof(short) * (size_t)rows * HH * DD);

  hipMemsetAsync(z0, 0, zlen, stream);

  k_ln<<<dim3((NS + 3) / 4), dim3(256), 0, stream>>>(x, gamma, beta, h, hbf,
                                                     ei, cntsrc, cntdst);
  k_cast_w2t2<<<dim3(HH * DD * DD / 256), dim3(256), 0, stream>>>(w2, w2t2);
  k_u<<<dim3((EE + 31) / 32), dim3(256), 0, stream>>>(ea, w1, b1, ubf);
  k_gemm64<<<dim3((NS + 31) / 32), dim3(256), 0, stream>>>(h, b2, cc, NS);
  k_scan<<<dim3(1), dim3(1024), 0, stream>>>(cntsrc, rowptr, cursor);
  k_scatter<<<dim3((EE + 255) / 256), dim3(256), 0, stream>>>(ei, cursor, eord);

  for (int n0 = 0; n0 < NS; n0 += rows) {
    int n1 = n0 + rows;
    if (n1 > NS) n1 = NS;
    int nr = n1 - n0;
    k_T_mfma<<<dim3((nr + 63) / 64, (HH * DD) / 256), dim3(256), 0, stream>>>(
        hbf, w2t2, Tt, n0, n1);
    k_msg_wave<<<dim3((nr + 3) / 4), dim3(256), 0, stream>>>(
        ubf, Tt, cc, ei, rowptr, eord, agg, n0, n1);
  }

  k_final<<<dim3((NS + 31) / 32), dim3(256), 0, stream>>>(x, h, root, bias, agg,
                                                          cntdst, out);
}

// Round 6
// 163.272 us; speedup vs baseline: 1.2089x; 1.2089x over previous
//
#include <hip/hip_runtime.h>

#define NS 10000
#define DD 64
#define HH 128
#define EE 50000
#define SLOPE 0.01f

typedef __attribute__((ext_vector_type(8))) short short8;
typedef __attribute__((ext_vector_type(4))) float f32x4;

static __device__ __forceinline__ unsigned short f2bf(float f) {
  unsigned int u = __float_as_uint(f);
  u += 0x7fff + ((u >> 16) & 1);   // round-to-nearest-even
  return (unsigned short)(u >> 16);
}

__device__ __forceinline__ float wave_sum64(float v) {
  #pragma unroll
  for (int m = 32; m >= 1; m >>= 1) v += __shfl_xor(v, m, 64);
  return v;
}

// h = leaky_relu(layer_norm(x)) (+bf16 copy). Folds: degree counts AND
// ea->bf16 cast (grid 2500x256 = 640k threads; cast needs 400k).
__global__ __launch_bounds__(256) void k_ln(const float* __restrict__ x,
    const float* __restrict__ gamma, const float* __restrict__ beta,
    float* __restrict__ h, unsigned short* __restrict__ hbf,
    const float* __restrict__ ea, unsigned short* __restrict__ eabf,
    const int* __restrict__ ei, int* __restrict__ cntsrc,
    int* __restrict__ cntdst) {
  int gid = blockIdx.x * 256 + threadIdx.x;
  if (gid < EE) {
    atomicAdd(&cntsrc[ei[gid]], 1);
    atomicAdd(&cntdst[ei[EE + gid]], 1);
  }
  if (gid < EE * DD / 8) {
    const float4* sp = (const float4*)(ea + (size_t)gid * 8);
    float4 v0 = sp[0], v1 = sp[1];
    short8 o;
    o[0] = f2bf(v0.x); o[1] = f2bf(v0.y); o[2] = f2bf(v0.z); o[3] = f2bf(v0.w);
    o[4] = f2bf(v1.x); o[5] = f2bf(v1.y); o[6] = f2bf(v1.z); o[7] = f2bf(v1.w);
    *(short8*)(eabf + (size_t)gid * 8) = o;
  }
  int wid = threadIdx.x >> 6;
  int lane = threadIdx.x & 63;
  int row = blockIdx.x * 4 + wid;
  if (row >= NS) return;
  float v = x[row * DD + lane];
  float s = wave_sum64(v);
  float s2 = wave_sum64(v * v);
  float mu = s * (1.0f / 64.0f);
  float var = s2 * (1.0f / 64.0f) - mu * mu;
  float r = rsqrtf(var + 1e-5f);
  float hn = (v - mu) * r * gamma[lane] + beta[lane];
  float hv = hn >= 0.f ? hn : SLOPE * hn;
  h[row * DD + lane] = hv;
  hbf[row * DD + lane] = f2bf(hv);
}

// w2t2[(f*128+k)*64 + d] = bf16(w2[k*4096 + d*64 + f])  (c2 = f*128+k order)
__global__ __launch_bounds__(256) void k_cast_w2t2(const float* __restrict__ w2,
    unsigned short* __restrict__ w2t2) {
  int tid = blockIdx.x * 256 + threadIdx.x;   // 524288
  int d = tid & 63;
  int c2 = tid >> 6;
  int f = c2 >> 7, k = c2 & 127;
  w2t2[tid] = f2bf(w2[k * (DD * DD) + d * DD + f]);
}

// ubf = bf16(leaky_relu(eabf @ w1 + b1)) via MFMA. Block: 64 rows x 128 cols.
__global__ __launch_bounds__(256) void k_u_mfma(
    const unsigned short* __restrict__ eabf, const float* __restrict__ w1,
    const float* __restrict__ b1, unsigned short* __restrict__ ubf) {
  __shared__ unsigned short As[64][72];
  __shared__ unsigned short Bs[HH][72];
  int t = threadIdx.x;
  int row0 = blockIdx.x * 64;
  #pragma unroll
  for (int i = 0; i < 2; ++i) {
    int idx = t + i * 256;
    int r = idx >> 3, c = (idx & 7) * 8;
    int gr = row0 + r;
    short8 v = {};
    if (gr < EE) v = *(const short8*)(eabf + (size_t)gr * DD + c);
    *(short8*)(&As[r][c]) = v;
  }
  #pragma unroll
  for (int i = 0; i < 32; ++i) {
    int idx = t + i * 256;          // 0..8191
    int hc = idx >> 6, d = idx & 63;
    Bs[hc][d] = f2bf(w1[d * HH + hc]);
  }
  __syncthreads();
  int w = t >> 6, lane = t & 63, lr = lane & 15, lg = lane >> 4;
  f32x4 acc[8] = {};
  #pragma unroll
  for (int kk = 0; kk < 64; kk += 32) {
    short8 a = *(const short8*)(&As[w * 16 + lr][kk + lg * 8]);
    #pragma unroll
    for (int ni = 0; ni < 8; ++ni) {
      short8 b = *(const short8*)(&Bs[ni * 16 + lr][kk + lg * 8]);
      acc[ni] = __builtin_amdgcn_mfma_f32_16x16x32_bf16(a, b, acc[ni], 0, 0, 0);
    }
  }
  #pragma unroll
  for (int ni = 0; ni < 8; ++ni) {
    int col = ni * 16 + lr;
    float bb = b1[col];
    #pragma unroll
    for (int r = 0; r < 4; ++r) {
      int gr = row0 + w * 16 + lg * 4 + r;
      if (gr < EE) {
        float vv = acc[ni][r] + bb;
        ubf[(size_t)gr * HH + col] = f2bf(vv >= 0.f ? vv : SLOPE * vv);
      }
    }
  }
}

// C[n,64] = A[n,64] @ B[64,64]
__global__ __launch_bounds__(256) void k_gemm64(const float* __restrict__ A,
    const float* __restrict__ B, float* __restrict__ C, int n) {
  __shared__ float Bs[DD][DD + 1];
  __shared__ float As[32][DD];
  int t = threadIdx.x;
  #pragma unroll
  for (int i = 0; i < 16; ++i) {
    int idx = t + i * 256;
    Bs[idx >> 6][idx & 63] = B[idx];
  }
  int row0 = blockIdx.x * 32;
  #pragma unroll
  for (int i = 0; i < 8; ++i) {
    int idx = t + i * 256;
    int r = idx >> 6, d = idx & 63;
    int gr = row0 + r;
    As[r][d] = (gr < n) ? A[gr * DD + d] : 0.f;
  }
  __syncthreads();
  int r = t >> 3;
  int c0 = (t & 7) * 8;
  int gr = row0 + r;
  if (gr >= n) return;
  float acc[8] = {};
  for (int d = 0; d < DD; ++d) {
    float a = As[r][d];
    #pragma unroll
    for (int j = 0; j < 8; ++j) acc[j] += a * Bs[d][c0 + j];
  }
  #pragma unroll
  for (int j = 0; j < 8; ++j) C[(size_t)gr * DD + c0 + j] = acc[j];
}

// single-block exclusive scan of cntsrc -> rowptr[N+1], also init cursor.
__global__ __launch_bounds__(1024) void k_scan(const int* __restrict__ cntsrc,
    int* __restrict__ rowptr, int* __restrict__ cursor) {
  __shared__ int ps[1024];
  int t = threadIdx.x;
  const int CH = (NS + 1023) / 1024;
  int base = t * CH;
  int sum = 0;
  for (int i = 0; i < CH; ++i) {
    int idx = base + i;
    if (idx < NS) sum += cntsrc[idx];
  }
  ps[t] = sum;
  __syncthreads();
  for (int off = 1; off < 1024; off <<= 1) {
    int v = (t >= off) ? ps[t - off] : 0;
    __syncthreads();
    ps[t] += v;
    __syncthreads();
  }
  int run = ps[t] - sum;
  for (int i = 0; i < CH; ++i) {
    int idx = base + i;
    if (idx < NS) {
      rowptr[idx] = run;
      cursor[idx] = run;
      run += cntsrc[idx];
    }
  }
  if (t == 1023) rowptr[NS] = run;
}

__global__ __launch_bounds__(256) void k_scatter(const int* __restrict__ ei,
    int* __restrict__ cursor, int* __restrict__ eord) {
  int e = blockIdx.x * 256 + threadIdx.x;
  if (e < EE) {
    int s = ei[e];
    int pos = atomicAdd(&cursor[s], 1);
    eord[pos] = e;
  }
}

// Tt[(n-n0)*8192 + c2] (bf16) = sum_d hbf[n,d] * w2t2[c2,d], c2 = f*128+k.
// Tile 64 rows x 256 cols, 4 waves. Epilogue: LDS transpose (reusing B-tile
// LDS) -> fully-coalesced short8 stores (512B runs per row).
__global__ __launch_bounds__(256) void k_T_mfma(
    const unsigned short* __restrict__ hbf, const unsigned short* __restrict__ w2t2,
    unsigned short* __restrict__ T, int n0, int n1) {
  __shared__ unsigned short As[64][72];
  __shared__ unsigned short Bs[256 * 72];   // after MFMA reused as Ts[64][264]
  int t = threadIdx.x;
  int row0 = n0 + blockIdx.x * 64;
  int col0 = blockIdx.y * 256;
  #pragma unroll
  for (int i = 0; i < 2; ++i) {
    int idx = t + i * 256;
    int r = idx >> 3, cc = (idx & 7) * 8;
    int gr = row0 + r;
    short8 v = {};
    if (gr < n1) v = *(const short8*)(hbf + (size_t)gr * DD + cc);
    *(short8*)(&As[r][cc]) = v;
  }
  #pragma unroll
  for (int i = 0; i < 8; ++i) {
    int idx = t + i * 256;
    int cL = idx >> 3, rr = (idx & 7) * 8;
    int gc = col0 + cL;
    short8 v = *(const short8*)(w2t2 + (size_t)gc * DD + rr);
    *(short8*)(&Bs[cL * 72 + rr]) = v;
  }
  __syncthreads();
  int w = t >> 6, lane = t & 63;
  int lr = lane & 15, lg = lane >> 4;
  f32x4 acc[4][4] = {};
  #pragma unroll
  for (int kk = 0; kk < 64; kk += 32) {
    short8 a[4], b[4];
    #pragma unroll
    for (int mi = 0; mi < 4; ++mi)
      a[mi] = *(const short8*)(&As[mi * 16 + lr][kk + lg * 8]);
    #pragma unroll
    for (int ni = 0; ni < 4; ++ni)
      b[ni] = *(const short8*)(&Bs[(w * 64 + ni * 16 + lr) * 72 + kk + lg * 8]);
    #pragma unroll
    for (int mi = 0; mi < 4; ++mi)
      #pragma unroll
      for (int ni = 0; ni < 4; ++ni)
        acc[mi][ni] = __builtin_amdgcn_mfma_f32_16x16x32_bf16(
            a[mi], b[ni], acc[mi][ni], 0, 0, 0);
  }
  __syncthreads();   // all waves done reading Bs
  #pragma unroll
  for (int mi = 0; mi < 4; ++mi)
    #pragma unroll
    for (int ni = 0; ni < 4; ++ni) {
      int col = w * 64 + ni * 16 + lr;
      #pragma unroll
      for (int reg = 0; reg < 4; ++reg)
        Bs[(mi * 16 + lg * 4 + reg) * 264 + col] = f2bf(acc[mi][ni][reg]);
    }
  __syncthreads();
  #pragma unroll
  for (int i = 0; i < 8; ++i) {
    int idx = t + i * 256;           // 0..2047
    int row = idx >> 5, seg = idx & 31;
    int gr = row0 + row;
    if (gr < n1) {
      short8 v = *(const short8*)(&Bs[row * 264 + seg * 8]);
      *(short8*)(T + (size_t)(gr - n0) * (HH * DD) + col0 + seg * 8) = v;
    }
  }
}

// Wave-per-node message pass: B-frags = Tt[s] (16KB, read once), A-frags =
// gathered bf16 u-rows of <=16 edges; 16 MFMA -> msg tile; +cc; atomic flush.
__global__ __launch_bounds__(256) void k_msg_wave(
    const unsigned short* __restrict__ ubf, const unsigned short* __restrict__ T,
    const float* __restrict__ cc, const int* __restrict__ ei,
    const int* __restrict__ rowptr, const int* __restrict__ eord,
    float* __restrict__ agg, int n0, int n1) {
  int wid = threadIdx.x >> 6;
  int lane = threadIdx.x & 63;
  int s = n0 + blockIdx.x * 4 + wid;
  if (s >= n1) return;
  int beg = rowptr[s];
  int deg = rowptr[s + 1] - beg;
  if (deg == 0) return;
  int lr = lane & 15, lg = lane >> 4;
  const unsigned short* tp = T + (size_t)(s - n0) * (HH * DD);
  short8 b[4][4];   // [ftile][kstep]
  #pragma unroll
  for (int ft = 0; ft < 4; ++ft)
    #pragma unroll
    for (int kk = 0; kk < 4; ++kk)
      b[ft][kk] =
          *(const short8*)(tp + (ft * 16 + lr) * HH + kk * 32 + lg * 8);
  float clv[4];
  #pragma unroll
  for (int ft = 0; ft < 4; ++ft) clv[ft] = cc[(size_t)s * DD + ft * 16 + lr];

  for (int p0 = 0; p0 < deg; p0 += 16) {
    int ev = 0, dv = 0;
    if (lane < 16 && p0 + lane < deg) {
      ev = eord[beg + p0 + lane];
      dv = ei[EE + ev];
    }
    int e_lr = __shfl(ev, (p0 + lr < deg) ? lr : 0);
    const unsigned short* up = ubf + (size_t)e_lr * HH;
    short8 a[4];
    #pragma unroll
    for (int kk = 0; kk < 4; ++kk)
      a[kk] = *(const short8*)(up + kk * 32 + lg * 8);
    f32x4 acc[4] = {};
    #pragma unroll
    for (int kk = 0; kk < 4; ++kk)
      #pragma unroll
      for (int ft = 0; ft < 4; ++ft)
        acc[ft] = __builtin_amdgcn_mfma_f32_16x16x32_bf16(a[kk], b[ft][kk],
                                                          acc[ft], 0, 0, 0);
    #pragma unroll
    for (int r = 0; r < 4; ++r) {
      int idx = p0 + lg * 4 + r;
      int dstn = __shfl(dv, lg * 4 + r);
      if (idx < deg) {
        #pragma unroll
        for (int ft = 0; ft < 4; ++ft)
          atomicAdd(&agg[(size_t)dstn * DD + ft * 16 + lr],
                    acc[ft][r] + clv[ft]);
      }
    }
  }
}

// out = x + agg/max(cnt,1) + h@root + bias
__global__ __launch_bounds__(256) void k_final(const float* __restrict__ x,
    const float* __restrict__ h, const float* __restrict__ root,
    const float* __restrict__ bias, const float* __restrict__ agg,
    const int* __restrict__ cnt, float* __restrict__ out) {
  __shared__ float Bs[DD][DD + 1];
  __shared__ float As[32][DD];
  int t = threadIdx.x;
  #pragma unroll
  for (int i = 0; i < 16; ++i) {
    int idx = t + i * 256;
    Bs[idx >> 6][idx & 63] = root[idx];
  }
  int row0 = blockIdx.x * 32;
  #pragma unroll
  for (int i = 0; i < 8; ++i) {
    int idx = t + i * 256;
    int r = idx >> 6, d = idx & 63;
    int gr = row0 + r;
    As[r][d] = (gr < NS) ? h[gr * DD + d] : 0.f;
  }
  __syncthreads();
  int r = t >> 3;
  int c0 = (t & 7) * 8;
  int gr = row0 + r;
  if (gr >= NS) return;
  float acc[8] = {};
  for (int d = 0; d < DD; ++d) {
    float a = As[r][d];
    #pragma unroll
    for (int j = 0; j < 8; ++j) acc[j] += a * Bs[d][c0 + j];
  }
  float inv = 1.0f / fmaxf((float)cnt[gr], 1.0f);
  #pragma unroll
  for (int j = 0; j < 8; ++j) {
    size_t gi = (size_t)gr * DD + c0 + j;
    out[gi] = x[gi] + agg[gi] * inv + acc[j] + bias[c0 + j];
  }
}

extern "C" void kernel_launch(void* const* d_in, const int* in_sizes, int n_in,
                              void* d_out, int out_size, void* d_ws, size_t ws_size,
                              hipStream_t stream) {
  const float* x     = (const float*)d_in[0];
  const float* ea    = (const float*)d_in[1];
  const float* gamma = (const float*)d_in[2];
  const float* beta  = (const float*)d_in[3];
  const float* w1    = (const float*)d_in[4];
  const float* b1    = (const float*)d_in[5];
  const float* w2    = (const float*)d_in[6];
  const float* b2    = (const float*)d_in[7];
  const float* root  = (const float*)d_in[8];
  const float* bias  = (const float*)d_in[9];
  const int*   ei    = (const int*)d_in[10];
  float* out = (float*)d_out;

  char* p = (char*)d_ws;
  auto carve = [&](size_t bytes) {
    char* q = p;
    p += (bytes + 255) & ~(size_t)255;
    return q;
  };
  float* h             = (float*)carve(sizeof(float) * NS * DD);
  unsigned short* hbf  = (unsigned short*)carve(sizeof(short) * NS * DD);
  float* cc            = (float*)carve(sizeof(float) * NS * DD);
  unsigned short* w2t2 = (unsigned short*)carve(sizeof(short) * HH * DD * DD);
  unsigned short* eabf = (unsigned short*)carve(sizeof(short) * (size_t)EE * DD);
  unsigned short* ubf  = (unsigned short*)carve(sizeof(short) * (size_t)EE * HH);
  int* rowptr          = (int*)carve(sizeof(int) * (NS + 1));
  int* cursor          = (int*)carve(sizeof(int) * NS);
  int* eord            = (int*)carve(sizeof(int) * EE);
  // contiguous zero-region: agg | cntdst | cntsrc (single memset)
  char* z0 = p;
  float* agg           = (float*)carve(sizeof(float) * NS * DD);
  int* cntdst          = (int*)carve(sizeof(int) * NS);
  int* cntsrc          = (int*)carve(sizeof(int) * NS);
  size_t zlen = (size_t)(p - z0);
  size_t fixed = (size_t)(p - (char*)d_ws);

  // T buffer: full NS if it fits (round-4 evidence: ws = 256 MiB -> it does).
  size_t freeb = (ws_size > fixed) ? (ws_size - fixed - 256) : 0;
  int rows = (int)(freeb / (sizeof(short) * HH * DD));
  if (rows > NS) rows = NS;
  rows &= ~63;
  if (rows < 64) rows = 64;
  unsigned short* Tt = (unsigned short*)carve(sizeof(short) * (size_t)rows * HH * DD);

  hipMemsetAsync(z0, 0, zlen, stream);

  k_ln<<<dim3((NS + 3) / 4), dim3(256), 0, stream>>>(x, gamma, beta, h, hbf,
                                                     ea, eabf, ei, cntsrc, cntdst);
  k_cast_w2t2<<<dim3(HH * DD * DD / 256), dim3(256), 0, stream>>>(w2, w2t2);
  k_u_mfma<<<dim3((EE + 63) / 64), dim3(256), 0, stream>>>(eabf, w1, b1, ubf);
  k_gemm64<<<dim3((NS + 31) / 32), dim3(256), 0, stream>>>(h, b2, cc, NS);
  k_scan<<<dim3(1), dim3(1024), 0, stream>>>(cntsrc, rowptr, cursor);
  k_scatter<<<dim3((EE + 255) / 256), dim3(256), 0, stream>>>(ei, cursor, eord);

  for (int n0 = 0; n0 < NS; n0 += rows) {
    int n1 = n0 + rows;
    if (n1 > NS) n1 = NS;
    int nr = n1 - n0;
    k_T_mfma<<<dim3((nr + 63) / 64, (HH * DD) / 256), dim3(256), 0, stream>>>(
        hbf, w2t2, Tt, n0, n1);
    k_msg_wave<<<dim3((nr + 3) / 4), dim3(256), 0, stream>>>(
        ubf, Tt, cc, ei, rowptr, eord, agg, n0, n1);
  }

  k_final<<<dim3((NS + 31) / 32), dim3(256), 0, stream>>>(x, h, root, bias, agg,
                                                          cntdst, out);
}